// Round 9
// baseline (1626.209 us; speedup 1.0000x reference)
//
#include <hip/hip_runtime.h>
#include <math.h>

// NaryTreeLSTM on MI355X — round 19: persistent lower tree, fixed.
// R18 post-mortem (542us, Occ 3.8%): (a) 80 blocks = 0.3 waves/SIMD, zero
// latency hiding; (b) pre[] round-tripped 21MB through HBM between phases;
// (c) 23 barriers with s_sleep(1) spin hammered the coherent counter line.
// R19: 512 blocks (launch_bounds(256,4) -> <=128 VGPR -> 4 blocks/CU
// co-residency cap 1024); epilogue fused INTO the gemm wave (R17's proven
// in-register math; unit = 16 rows x 16 cols x 5 gates, acc[5]) -> no pre,
// 12 barriers instead of 23; s_sleep(127) backoff. d=12 joins the persistent
// kernel (units balance at 4096 over 2048 waves); 128^2 gemm deleted.
// Upper pipeline (leaf + d=15..13 big gemm + combine_v) = R16 verbatim.

#define LEAF_N 65536
#define NBLK 512
#define NWAVE (NBLK * 4)

typedef __attribute__((ext_vector_type(8))) short bf16x8;
typedef __attribute__((ext_vector_type(4))) float f32x4;
typedef __attribute__((ext_vector_type(8))) float f32x8;
typedef __attribute__((ext_vector_type(8))) _Float16 f16x8;
typedef unsigned short u16;

__device__ __forceinline__ float fast_sig(float x) {
    return __builtin_amdgcn_rcpf(1.0f + __expf(-x));
}
__device__ __forceinline__ float fast_tanh(float x) {
    return 2.0f * __builtin_amdgcn_rcpf(1.0f + __expf(-2.0f * x)) - 1.0f;
}

__device__ __forceinline__ u16 f2bf(float f) {
    union { float f; unsigned u; } v; v.f = f;
    unsigned r = v.u + 0x7fffu + ((v.u >> 16) & 1u);   // RNE
    return (u16)(r >> 16);
}

// row-major Z offset (elems) for level d in [0,15]; levels are contiguous.
__host__ __device__ __forceinline__ size_t zrowOff(int d) {
    return (size_t)(65536 - (2 << d)) * 512;
}

__device__ __forceinline__ void gld_lds16(const u16* g, u16* s) {
    __builtin_amdgcn_global_load_lds(
        (const __attribute__((address_space(1))) void*)g,
        (__attribute__((address_space(3))) void*)s, 16, 0, 0);
}

// device-scope grid barrier; 512 co-resident blocks; long-backoff spin.
__device__ __forceinline__ void gbar(unsigned* cnt, unsigned& ph) {
    __syncthreads();
    ++ph;
    if (threadIdx.x == 0) {
        __threadfence();
        __hip_atomic_fetch_add(cnt, 1u, __ATOMIC_ACQ_REL, __HIP_MEMORY_SCOPE_AGENT);
        const unsigned tgt = ph * NBLK;
        while (__hip_atomic_load(cnt, __ATOMIC_ACQUIRE,
                                 __HIP_MEMORY_SCOPE_AGENT) < tgt)
            __builtin_amdgcn_s_sleep(127);
    }
    __syncthreads();
    __threadfence();
}

// ---------------- weight packing ----------------
// Wrow: row-major 1280x512 ([i|Ui],[o|Uo],[u|Uu],[f|Wfk0],[f|Wfk1])
// Wfrag: frag-major same matrix (lower_levels gemm):
//   addr = ((nt*16+kc)*64 + l)*8 + j ; row=nt*16+(l&15), k=kc*32+(l>>4)*8+j
// WleafRow: row-major 768x256 ([i;o;u])
__global__ __launch_bounds__(256) void pack_weights(
    const float* __restrict__ Wi, const float* __restrict__ bi,
    const float* __restrict__ Wf, const float* __restrict__ bf,
    const float* __restrict__ Wo, const float* __restrict__ bo,
    const float* __restrict__ Wu, const float* __restrict__ bu,
    const float* __restrict__ Ui, const float* __restrict__ Uo,
    const float* __restrict__ Uu, const float* __restrict__ Wfk,
    u16* __restrict__ Wrow, u16* __restrict__ Wfrag, u16* __restrict__ WleafRow,
    float* __restrict__ bbig, float* __restrict__ bleaf,
    unsigned* __restrict__ barcnt)
{
    int idx = blockIdx.x * 256 + threadIdx.x;
    const int NWB = 1280 * 512;
    const int NWL = 768 * 256;

    auto bigval = [&](int row, int k) -> float {
        int g = row >> 8, rr = row & 255;
        if (k < 256) {
            const float* W = (g == 0) ? Wi : (g == 1) ? Wo : (g == 2) ? Wu : Wf;
            return W[rr * 256 + k];
        }
        int kk = k - 256;
        return (g == 0) ? Ui[rr * 256 + kk]
             : (g == 1) ? Uo[rr * 256 + kk]
             : (g == 2) ? Uu[rr * 256 + kk]
             : (g == 3) ? Wfk[rr * 256 + kk]
                        : Wfk[65536 + rr * 256 + kk];
    };

    if (idx < NWB) {
        Wrow[idx] = f2bf(bigval(idx >> 9, idx & 511));
    } else if (idx < 2 * NWB) {
        int q = idx - NWB;
        int j = q & 7, l = (q >> 3) & 63, kc = (q >> 9) & 15, nt = q >> 13;
        int row = nt * 16 + (l & 15);
        int k = kc * 32 + ((l >> 4) << 3) + j;
        Wfrag[q] = f2bf(bigval(row, k));
    } else if (idx < 2 * NWB + NWL) {
        int q = idx - 2 * NWB;
        int r = q >> 8, k = q & 255;
        int g = r >> 8, rr = r & 255;
        const float* W = (g == 0) ? Wi : (g == 1) ? Wo : Wu;
        WleafRow[q] = f2bf(W[rr * 256 + k]);
    } else if (idx < 2 * NWB + NWL + 1280) {
        int r = idx - 2 * NWB - NWL;
        int g = r >> 8, rr = r & 255;
        bbig[r] = (g == 0) ? bi[rr] : (g == 1) ? bo[rr] : (g == 2) ? bu[rr] : bf[rr];
    } else if (idx < 2 * NWB + NWL + 1280 + 768) {
        int r = idx - 2 * NWB - NWL - 1280;
        int g = r >> 8, rr = r & 255;
        bleaf[r] = (g == 0) ? bi[rr] : (g == 1) ? bo[rr] : bu[rr];
    } else if (idx == 2 * NWB + NWL + 1280 + 768) {
        *barcnt = 0u;                       // reset persistent-kernel barrier
    }
}

// ---------------- x -> bf16 conversion ----------------
// internal rows (all levels 0..15): row-major Zrow; leaves: Xbf.
__global__ __launch_bounds__(256) void cvt_all(
    const float* __restrict__ x, u16* __restrict__ Zrow,
    u16* __restrict__ Xbf)
{
    int idx = blockIdx.x * 256 + threadIdx.x;
    if (idx >= 131071 * 32) return;
    int row = idx >> 5, k8 = idx & 31;
    const float* s = x + (size_t)row * 256 + k8 * 8;
    u16 r[8];
#pragma unroll
    for (int i = 0; i < 8; i++) r[i] = f2bf(s[i]);
    if (row < 65535) {
        int d = 31 - __clz(row + 1);
        int jn = row - ((1 << d) - 1);
        *(uint4*)(Zrow + zrowOff(d) + (size_t)jn * 512 + k8 * 8) = *(uint4*)r;
    } else {
        int jn = row - 65535;
        *(uint4*)(Xbf + (size_t)jn * 256 + k8 * 8) = *(uint4*)r;
    }
}

// ---------------- stage 1a: big-level GEMM (256x256, dbuf 2-phase) --------
template<int KD, int NC>
__global__ __launch_bounds__(512, 2) void gate_gemm_big(
    const u16* __restrict__ A, const u16* __restrict__ B,
    const float* __restrict__ bias, _Float16* __restrict__ G)
{
    constexpr int NT = KD / 64;
    extern __shared__ u16 S[];           // [2][A:16384 | B:16384]

    const int tid  = threadIdx.x;
    const int wave = tid >> 6;
    const int lane = tid & 63;
    const int bm = blockIdx.x * 256;
    const int bn = blockIdx.y * 256;

    const int srow = lane >> 3;
    const int scol = ((lane & 7) ^ srow) * 8;

    const int wr = wave >> 2;
    const int wc = wave & 3;
    const int lm = lane & 15, q4 = lane >> 4;

    auto stage = [&](int bi, int t) {
#pragma unroll
        for (int q = 0; q < 4; ++q) {
            const int g = wave * 4 + q;
            const int r = g * 8 + srow;
            gld_lds16(A + (size_t)(bm + r) * KD + t * 64 + scol,
                      S + bi * 32768 + g * 512 + lane * 8);
            gld_lds16(B + (size_t)(bn + r) * KD + t * 64 + scol,
                      S + bi * 32768 + 16384 + g * 512 + lane * 8);
        }
    };

    f32x4 acc[8][4] = {};

    stage(0, 0);
    __syncthreads();

#pragma unroll
    for (int t = 0; t < NT; ++t) {
        if (t + 1 < NT) stage((t + 1) & 1, t + 1);

        const u16* Ab = S + (t & 1) * 32768;
        const u16* Bb = Ab + 16384;
#pragma unroll
        for (int kk = 0; kk < 64; kk += 32) {
            const int sw = ((((kk >> 3) + q4) ^ (lm & 7)) << 3);
            bf16x8 af[8], bfr[4];
#pragma unroll
            for (int i = 0; i < 8; i++)
                af[i] = *(const bf16x8*)(Ab + (wr * 128 + i * 16 + lm) * 64 + sw);
#pragma unroll
            for (int j = 0; j < 4; j++)
                bfr[j] = *(const bf16x8*)(Bb + (wc * 64 + j * 16 + lm) * 64 + sw);
#pragma unroll
            for (int i = 0; i < 8; i++)
#pragma unroll
                for (int j = 0; j < 4; j++)
                    acc[i][j] = __builtin_amdgcn_mfma_f32_16x16x32_bf16(
                        af[i], bfr[j], acc[i][j], 0, 0, 0);
        }
        __syncthreads();
    }

    const int cr0 = q4 * 4;
#pragma unroll
    for (int i = 0; i < 8; i++) {
#pragma unroll
        for (int j = 0; j < 4; j++) {
            const int cg = bn + wc * 64 + j * 16 + lm;
            const float bb = bias[cg];
            const bool istan = ((cg >> 8) == 2);
#pragma unroll
            for (int reg = 0; reg < 4; reg++) {
                const int rr = bm + wr * 128 + i * 16 + cr0 + reg;
                float v = acc[i][j][reg] + bb;
                G[(size_t)rr * NC + cg] =
                    (_Float16)(istan ? fast_tanh(v) : fast_sig(v));
            }
        }
    }
}

// ---------------- stage 2: vectorized combine (z row-major) --------
template<bool LEAF>
__global__ __launch_bounds__(256) void combine_v(
    const _Float16* __restrict__ G, const float* __restrict__ csrc,
    float* __restrict__ cdst, u16* __restrict__ zrow_parent)
{
    constexpr int NC = LEAF ? 768 : 1280;
    const int t  = threadIdx.x;
    const int p  = blockIdx.x * 8 + (t >> 5);      // global pair index
    const int h0 = (t & 31) * 8;

    const _Float16* G0 = G + (size_t)(2 * p) * NC + h0;
    const _Float16* G1 = G0 + NC;

    f16x8 i0 = *(const f16x8*)(G0);
    f16x8 o0 = *(const f16x8*)(G0 + 256);
    f16x8 u0 = *(const f16x8*)(G0 + 512);
    f16x8 i1 = *(const f16x8*)(G1);
    f16x8 o1 = *(const f16x8*)(G1 + 256);
    f16x8 u1 = *(const f16x8*)(G1 + 512);

    f32x8 c0, c1;
#pragma unroll
    for (int e = 0; e < 8; e++) {
        c0[e] = (float)i0[e] * (float)u0[e];
        c1[e] = (float)i1[e] * (float)u1[e];
    }
    if (!LEAF) {
        f16x8 f00 = *(const f16x8*)(G0 + 768);
        f16x8 f10 = *(const f16x8*)(G0 + 1024);
        f16x8 f01 = *(const f16x8*)(G1 + 768);
        f16x8 f11 = *(const f16x8*)(G1 + 1024);
        const float* cs = csrc + (size_t)(4 * p) * 256 + h0;
        f32x8 cc0 = *(const f32x8*)(cs);
        f32x8 cc1 = *(const f32x8*)(cs + 256);
        f32x8 cc2 = *(const f32x8*)(cs + 512);
        f32x8 cc3 = *(const f32x8*)(cs + 768);
#pragma unroll
        for (int e = 0; e < 8; e++) {
            c0[e] += (float)f00[e] * cc0[e] + (float)f10[e] * cc1[e];
            c1[e] += (float)f01[e] * cc2[e] + (float)f11[e] * cc3[e];
        }
    }

    u16 hs[8];
#pragma unroll
    for (int e = 0; e < 8; e++) {
        float h0v = (float)o0[e] * fast_tanh(c0[e]);
        float h1v = (float)o1[e] * fast_tanh(c1[e]);
        hs[e] = f2bf(h0v + h1v);
    }

    float* cd = cdst + (size_t)(2 * p) * 256 + h0;
    *(f32x8*)(cd) = c0;
    *(f32x8*)(cd + 256) = c1;

    *(uint4*)(zrow_parent + (size_t)p * 512 + 256 + h0) = *(uint4*)hs;
}

// ---------------- persistent lower-tree kernel (d=12..0) ----------------
// 512 blocks x 256 thr (co-resident; <=128 VGPR via launch_bounds).
// Unit = one wave: 16 rows (rowgroup rgI) x 16 cols (cq) x 5 gates,
// acc[5] f32x4; A-frags from row-major Zrow, B-frags from frag-major Wfrag
// (L2-resident). Epilogue fused in-registers (R17-validated math):
// c -> cdst, sibling h-sums -> parent z; root (d=0) -> out.
// ONE grid barrier per level transition (12 total).
__global__ __launch_bounds__(256, 4) void lower_levels(
    u16* __restrict__ Zrow, const u16* __restrict__ Wfrag,
    const float* __restrict__ bbig, float* __restrict__ cA,
    float* __restrict__ cB, float* __restrict__ out,
    unsigned* __restrict__ cnt)
{
    const int tid  = threadIdx.x;
    const int lane = tid & 63;
    const int gw   = blockIdx.x * 4 + (tid >> 6);     // 0..NWAVE-1
    const int cc = lane & 15, rq = (lane >> 4) * 4;
    unsigned ph = 0;

    for (int d = 12; d >= 0; --d) {
        const int n = 1 << d;
        const u16* Z = Zrow + zrowOff(d);
        const float* csrc = (d & 1) ? cA : cB;
        float* cdst       = (d & 1) ? cB : cA;
        u16* zp = (d > 0) ? (Zrow + zrowOff(d - 1)) : nullptr;
        const int units = ((n + 15) >> 4) * 16;

        for (int u = gw; u < units; u += NWAVE) {
            const int rgI = u >> 4;
            const int cq  = u & 15;
            int rowA = rgI * 16 + cc; if (rowA >= n) rowA = n - 1;
            const u16* aB = Z + (size_t)rowA * 512 + ((lane >> 4) << 3);

            f32x4 acc[5] = {};
#pragma unroll
            for (int kc = 0; kc < 16; ++kc) {
                bf16x8 av = *(const bf16x8*)(aB + kc * 32);
#pragma unroll
                for (int g = 0; g < 5; ++g) {
                    const int nt = g * 16 + cq;
                    bf16x8 bv = *(const bf16x8*)(Wfrag +
                        ((size_t)(nt * 16 + kc) * 64 + lane) * 8);
                    acc[g] = __builtin_amdgcn_mfma_f32_16x16x32_bf16(
                        av, bv, acc[g], 0, 0, 0);
                }
            }

            const int col = cq * 16 + cc;
            const float bI = bbig[col],        bO = bbig[256 + col];
            const float bU = bbig[512 + col],  bF0 = bbig[768 + col];
            const float bF1 = bbig[1024 + col];
            float cv[4], hv[4];
#pragma unroll
            for (int r = 0; r < 4; ++r) {
                const int row = rgI * 16 + rq + r;
                float c = 0.f, h = 0.f;
                if (row < n) {
                    float iv = fast_sig(acc[0][r] + bI);
                    float ov = fast_sig(acc[1][r] + bO);
                    float uv = fast_tanh(acc[2][r] + bU);
                    float f0 = fast_sig(acc[3][r] + bF0);
                    float f1 = fast_sig(acc[4][r] + bF1);
                    c = iv * uv
                      + f0 * csrc[(size_t)(2 * row) * 256 + col]
                      + f1 * csrc[(size_t)(2 * row + 1) * 256 + col];
                    h = ov * fast_tanh(c);
                }
                cv[r] = c; hv[r] = h;
            }
            if (d == 0) {
                if (rq == 0) { out[col] = hv[0]; out[256 + col] = cv[0]; }
            } else {
#pragma unroll
                for (int r = 0; r < 4; ++r) {
                    const int row = rgI * 16 + rq + r;
                    if (row < n) cdst[(size_t)row * 256 + col] = cv[r];
                }
#pragma unroll
                for (int s = 0; s < 2; ++s) {
                    const int row = rgI * 16 + rq + 2 * s;
                    if (row < n)
                        zp[(size_t)(rgI * 8 + (rq >> 1) + s) * 512 + 256 + col]
                            = f2bf(hv[2 * s] + hv[2 * s + 1]);
                }
            }
        }
        if (d > 0) gbar(cnt, ph);
    }
}

// ---------------- launch ----------------
extern "C" void kernel_launch(void* const* d_in, const int* in_sizes, int n_in,
                              void* d_out, int out_size, void* d_ws, size_t ws_size,
                              hipStream_t stream)
{
    const float* x   = (const float*)d_in[0];
    const float* Wi  = (const float*)d_in[1];
    const float* bi  = (const float*)d_in[2];
    const float* Wf  = (const float*)d_in[3];
    const float* bf  = (const float*)d_in[4];
    const float* Wo  = (const float*)d_in[5];
    const float* bo  = (const float*)d_in[6];
    const float* Wu  = (const float*)d_in[7];
    const float* bu  = (const float*)d_in[8];
    const float* Ui  = (const float*)d_in[9];
    const float* Uo  = (const float*)d_in[10];
    const float* Uu  = (const float*)d_in[11];
    const float* Wfk = (const float*)d_in[12];
    float* out = (float*)d_out;
    char* ws   = (char*)d_ws;
    (void)ws_size; (void)in_sizes; (void)n_in; (void)out_size;

    size_t off = 0;
    u16* Wrow     = (u16*)(ws + off); off += (size_t)1280 * 512 * 2;
    u16* Wfrag    = (u16*)(ws + off); off += (size_t)1280 * 512 * 2;
    u16* WleafRow = (u16*)(ws + off); off += (size_t)768 * 256 * 2;
    float* bbig   = (float*)(ws + off); off += 1280 * 4;
    float* bleaf  = (float*)(ws + off); off += 768 * 4;
    unsigned* barcnt = (unsigned*)(ws + off); off += 256;                    // align
    u16* Xbf    = (u16*)(ws + off); off += (size_t)65536 * 256 * 2;          // 32 MB
    u16* Zrow   = (u16*)(ws + off); off += (size_t)65536 * 512 * 2;          // 64 MB
    float* cA = (float*)(ws + off); off += (size_t)65536 * 256 * 4;          // 64 MB
    float* cB = (float*)(ws + off); off += (size_t)32768 * 256 * 4;          // 32 MB
    _Float16* Ghalf = (_Float16*)(ws + off); off += (size_t)65536 * 768 * 2; // 96 MB

    // allow 128KB dynamic LDS for the big gemm (host-side, idempotent)
    static bool attr_set = false;
    if (!attr_set) {
        hipFuncSetAttribute((const void*)gate_gemm_big<512, 1280>,
                            hipFuncAttributeMaxDynamicSharedMemorySize, 131072);
        hipFuncSetAttribute((const void*)gate_gemm_big<256, 768>,
                            hipFuncAttributeMaxDynamicSharedMemorySize, 131072);
        attr_set = true;
    }

    // 1) pack weights (+ reset barrier counter) + convert x
    pack_weights<<<5897, 256, 0, stream>>>(Wi, bi, Wf, bf, Wo, bo, Wu, bu,
                                           Ui, Uo, Uu, Wfk, Wrow, Wfrag, WleafRow,
                                           bbig, bleaf, barcnt);
    cvt_all<<<16385, 256, 0, stream>>>(x, Zrow, Xbf);

    // 2) leaf: gemm (i,o,u fp16) + combine -> cA, Hs into Zrow level 15
    gate_gemm_big<256, 768><<<dim3(LEAF_N / 256, 3), 512, 131072, stream>>>(
        Xbf, WleafRow, bleaf, Ghalf);
    combine_v<true><<<LEAF_N / 16, 256, 0, stream>>>(
        Ghalf, nullptr, cA, Zrow + zrowOff(15));

    // 3) big internal levels d=15..13
    for (int d = 15; d >= 13; d--) {
        int n = 1 << d;
        float* csrc = (d & 1) ? cA : cB;
        float* cdst = (d & 1) ? cB : cA;
        gate_gemm_big<512, 1280><<<dim3(n / 256, 5), 512, 131072, stream>>>(
            Zrow + zrowOff(d), Wrow, bbig, Ghalf);
        combine_v<false><<<n / 16, 256, 0, stream>>>(
            Ghalf, csrc, cdst, Zrow + zrowOff(d - 1));
    }

    // 4) persistent lower tree: d=12..0 (root writes out)
    lower_levels<<<NBLK, 256, 0, stream>>>(
        Zrow, Wfrag, bbig, cA, cB, out, barcnt);
}